// Round 4
// baseline (341.223 us; speedup 1.0000x reference)
//
#include <hip/hip_runtime.h>
#include <hip/hip_bf16.h>

using bf16 = __hip_bfloat16;
typedef __attribute__((ext_vector_type(8))) short bf16x8;   // 8 bf16 in 4 VGPRs
typedef __attribute__((ext_vector_type(4))) short bf16x4;   // 4 bf16 in 2 VGPRs
typedef __attribute__((ext_vector_type(4))) float f32x4;

// async global->LDS, 16B per lane; LDS dest = wave-uniform base + lane*16
typedef const __attribute__((address_space(1))) void* as1_t;
typedef __attribute__((address_space(3))) void* as3_t;
__device__ __forceinline__ void load_lds16(const void* g, void* l) {
    __builtin_amdgcn_global_load_lds((as1_t)g, (as3_t)l, 16, 0, 0);
}

// ---------------- elementwise cast f32 -> bf16 (x) ----------------
__global__ __launch_bounds__(256) void cast_f32_bf16(const float* __restrict__ src,
                                                     bf16* __restrict__ dst, int n4) {
    int i = (blockIdx.x * 256 + threadIdx.x);
    if (i >= n4) return;
    const float4 v = *(const float4*)(src + (long)i * 4);
    bf16 t[4];
    t[0] = __float2bfloat16(v.x);
    t[1] = __float2bfloat16(v.y);
    t[2] = __float2bfloat16(v.z);
    t[3] = __float2bfloat16(v.w);
    *(uint2*)(dst + (long)i * 4) = *(uint2*)t;
}

// ---------------- tiled transpose-cast: src[K][N] f32 -> dst[N][K] bf16 ----------------
__global__ __launch_bounds__(256) void transpose_cast(const float* __restrict__ src,
                                                      int K, int N, bf16* __restrict__ dst) {
    __shared__ float tile[32][33];
    const int tx = threadIdx.x & 31;
    const int ty = threadIdx.x >> 5;   // 0..7
    const int n0 = blockIdx.x * 32;
    const int k0 = blockIdx.y * 32;
    for (int i = 0; i < 32; i += 8)
        tile[ty + i][tx] = src[(long)(k0 + ty + i) * N + n0 + tx];
    __syncthreads();
    for (int i = 0; i < 32; i += 8)
        dst[(long)(n0 + ty + i) * K + k0 + tx] = __float2bfloat16(tile[tx][ty + i]);
}

// ---------------- V transpose via LDS tile: qkv[8192][1536] -> vt[b][kvh][64][2048] ----------------
// grid: (T/64, NKV, B); both global sides coalesced (16B/lane).
__global__ __launch_bounds__(256) void transpose_v(const bf16* __restrict__ qkv,
                                                   bf16* __restrict__ vt) {
    __shared__ bf16 tile[64][72];
    const int tb = blockIdx.x, kvh = blockIdx.y, b = blockIdx.z;
    const int r = threadIdx.x >> 3;          // 0..31
    const int c = (threadIdx.x & 7) * 8;     // 0..56
    const bf16* src = qkv + (long)(b * 2048 + tb * 64) * 1536 + 1280 + kvh * 64;
    *(uint4*)&tile[r][c]      = *(const uint4*)(src + (long)r * 1536 + c);
    *(uint4*)&tile[r + 32][c] = *(const uint4*)(src + (long)(r + 32) * 1536 + c);
    __syncthreads();
    bf16* dst = vt + (long)(b * 4 + kvh) * 64 * 2048 + tb * 64;
#pragma unroll
    for (int rr = 0; rr < 2; rr++) {
        const int d = r + rr * 32;
        bf16 t8[8];
#pragma unroll
        for (int e = 0; e < 8; e++) t8[e] = tile[c + e][d];
        *(uint4*)(dst + (long)d * 2048 + c) = *(uint4*)t8;
    }
}

// ---------------- GEMM (m97 structure): C[M][N] = A[M][K] * Bt[N][K]^T ----------------
// 128x128 tile, BK=32, 256 threads; global_load_lds(16B) into unpadded swizzled LDS.
// Swizzle: within each 16-row group, data chunk (r,c) lives at slot c' = (c + (r>>1)) & 3
// -> frag ds_read_b128 lands on 8 distinct bank groups (2-way only, free).
template <bool BF16_OUT>
__global__ __launch_bounds__(256) void gemm_bt(const bf16* __restrict__ A,
                                               const bf16* __restrict__ Bt,
                                               void* __restrict__ C,
                                               int M, int N, int K) {
    __shared__ bf16 Ash[128 * 32];
    __shared__ bf16 Bsh[128 * 32];
    const int tid  = threadIdx.x;
    const int lane = tid & 63;
    const int wid  = tid >> 6;
    const int wm   = (wid >> 1) * 64;
    const int wn   = (wid & 1) * 64;
    const int quad = lane >> 4;
    const int l16  = lane & 15;
    const int bm = blockIdx.x, bn = blockIdx.y;

    // staging: wave covers rows [32*wid, 32*wid+32) of A and of B, 2 instrs each.
    const int r_l   = lane >> 2;                 // 0..15 (row within 16-group)
    const int cslot = lane & 3;                  // LDS slot chunk
    const int cdat  = (cslot - (r_l >> 1)) & 3;  // which global chunk this slot holds

    const bf16* pa0 = A  + (long)(bm * 128 + wid * 32 + r_l) * K + cdat * 8;
    const bf16* pa1 = pa0 + (long)16 * K;
    const bf16* pb0 = Bt + (long)(bn * 128 + wid * 32 + r_l) * K + cdat * 8;
    const bf16* pb1 = pb0 + (long)16 * K;
    bf16* la0 = Ash + (wid * 32) * 32;
    bf16* la1 = Ash + (wid * 32 + 16) * 32;
    bf16* lb0 = Bsh + (wid * 32) * 32;
    bf16* lb1 = Bsh + (wid * 32 + 16) * 32;

    const int sw = ((quad + (l16 >> 1)) & 3) * 8;   // swizzled chunk offset for frag reads

    f32x4 acc[4][4] = {};

    for (int k0 = 0; k0 < K; k0 += 32) {
        __syncthreads();                 // prior-iter LDS reads done (WAR)
        load_lds16(pa0 + k0, la0);
        load_lds16(pa1 + k0, la1);
        load_lds16(pb0 + k0, lb0);
        load_lds16(pb1 + k0, lb1);
        __syncthreads();                 // vmcnt(0) drain: tiles resident

        bf16x8 af[4], bfr[4];
#pragma unroll
        for (int i = 0; i < 4; i++) af[i]  = *(const bf16x8*)&Ash[(wm + i * 16 + l16) * 32 + sw];
#pragma unroll
        for (int j = 0; j < 4; j++) bfr[j] = *(const bf16x8*)&Bsh[(wn + j * 16 + l16) * 32 + sw];
#pragma unroll
        for (int i = 0; i < 4; i++)
#pragma unroll
            for (int j = 0; j < 4; j++)
                acc[i][j] = __builtin_amdgcn_mfma_f32_16x16x32_bf16(af[i], bfr[j], acc[i][j], 0, 0, 0);
    }

    // epilogue: C/D layout col=lane&15, row=quad*4+reg
#pragma unroll
    for (int i = 0; i < 4; i++) {
#pragma unroll
        for (int r = 0; r < 4; r++) {
            const long row = (long)(bm * 128 + wm + i * 16 + quad * 4 + r);
#pragma unroll
            for (int j = 0; j < 4; j++) {
                const int col = bn * 128 + wn + j * 16 + l16;
                const float v = acc[i][j][r];
                if (BF16_OUT) ((bf16*)C)[row * N + col] = __float2bfloat16(v);
                else          ((float*)C)[row * N + col] = v;
            }
        }
    }
}

// ---------------- flash attention v4: S^T trick, max-free softmax, 32q/wave, kv-tile 128 ----------------
// grid: (T/128, NH, B), 256 threads = 4 waves; block owns 128 q rows, wave owns 32 (2 m-frags).
// K[128][64] and Vt[64][128] staged in LDS once per 128 kv, shared by all 4 waves.
__global__ __launch_bounds__(256) void attn_kernel(const bf16* __restrict__ qkv,
                                                   const bf16* __restrict__ vt,
                                                   bf16* __restrict__ attn) {
    __shared__ bf16 Ksh[128][72];     // [kv][d]
    __shared__ bf16 Vsh[64][136];     // [d][kv]

    const int tid  = threadIdx.x;
    const int lane = tid & 63;
    const int wid  = tid >> 6;
    const int quad = lane >> 4;
    const int l16  = lane & 15;
    const int h    = blockIdx.y;
    const int b    = blockIdx.z;
    const int kvh  = h >> 2;
    const int qblock = (gridDim.x - 1 - blockIdx.x) * 128;   // heavy blocks first
    const int q0     = qblock + wid * 32;

    // Q fragments (B-operand for S^T): n = q = l16, k = d = kf*32 + quad*8 + j
    const bf16* qbase = qkv + (long)(b * 2048 + q0 + l16) * 1536 + h * 64;
    bf16x8 qf[2][2];
#pragma unroll
    for (int mf = 0; mf < 2; mf++)
#pragma unroll
        for (int kf = 0; kf < 2; kf++)
            qf[mf][kf] = *(const bf16x8*)(qbase + (long)mf * 16 * 1536 + kf * 32 + quad * 8);

    f32x4 o[2][4] = {};               // O^T per m-frag: q=l16, d = dt*16+quad*4+r
    float l_part[2] = {0.f, 0.f};     // per-lane softmax denominators (q = l16)
    const float ls = 0.125f * 1.44269504f;   // 1/sqrt(64) * log2(e)

    const bf16* kg = qkv + (long)(b * 2048) * 1536 + 1024 + kvh * 64;
    const bf16* vg = vt + (long)(b * 4 + kvh) * 64 * 2048;
    const int rK = tid >> 3, cK = (tid & 7) * 8;    // K rows: rK + 32i (128B/row coalesced)
    const int rV = tid >> 4, cV = (tid & 15) * 8;   // V rows: rV + 16i (256B/row coalesced)

    const int nIter = qblock / 128 + 1;
    for (int it = 0; it < nIter; ++it) {
        const int kv0 = it * 128;
        uint4 kr[4], vr[4];
#pragma unroll
        for (int i = 0; i < 4; i++)
            kr[i] = *(const uint4*)(kg + (long)(kv0 + rK + 32 * i) * 1536 + cK);
#pragma unroll
        for (int i = 0; i < 4; i++)
            vr[i] = *(const uint4*)(vg + (long)(rV + 16 * i) * 2048 + kv0 + cV);
        __syncthreads();   // WAR: prior iter LDS reads done
#pragma unroll
        for (int i = 0; i < 4; i++) *(uint4*)&Ksh[rK + 32 * i][cK] = kr[i];
#pragma unroll
        for (int i = 0; i < 4; i++) *(uint4*)&Vsh[rV + 16 * i][cV] = vr[i];
        __syncthreads();

        const bool last = (it == nIter - 1);
#pragma unroll
        for (int hf = 0; hf < 2; hf++) {
            if (last && (hf * 64 > wid * 32 + 31)) continue;   // wave fully masked

            // ---- S^T = K Q^T : s[mf][kvt]: q=l16, kv = hf*64 + kvt*16 + quad*4 + r ----
            f32x4 s[2][4] = {};
#pragma unroll
            for (int kvt = 0; kvt < 4; kvt++)
#pragma unroll
                for (int kf = 0; kf < 2; kf++) {
                    const bf16x8 kfr = *(const bf16x8*)&Ksh[hf * 64 + kvt * 16 + l16][kf * 32 + quad * 8];
#pragma unroll
                    for (int mf = 0; mf < 2; mf++)
                        s[mf][kvt] = __builtin_amdgcn_mfma_f32_16x16x32_bf16(kfr, qf[mf][kf], s[mf][kvt], 0, 0, 0);
                }

            // ---- causal mask (diagonal super-tile only) ----
            if (last && (hf * 64 + 63 > wid * 32)) {
#pragma unroll
                for (int mf = 0; mf < 2; mf++) {
                    const int q_loc = wid * 32 + mf * 16 + l16;
#pragma unroll
                    for (int kvt = 0; kvt < 4; kvt++)
#pragma unroll
                        for (int r = 0; r < 4; r++)
                            if (hf * 64 + kvt * 16 + quad * 4 + r > q_loc) s[mf][kvt][r] = -1e30f;
                }
            }

            // ---- p = exp2(s*ls); l accumulates per-lane; P feeds PV directly ----
#pragma unroll
            for (int kvt = 0; kvt < 4; kvt++) {
                bf16x4 pk[2];
#pragma unroll
                for (int mf = 0; mf < 2; mf++) {
                    bf16 tp[4];
#pragma unroll
                    for (int r = 0; r < 4; r++) {
                        const float p = exp2f(s[mf][kvt][r] * ls);
                        l_part[mf] += p;
                        tp[r] = __float2bfloat16(p);
                    }
                    pk[mf] = *(const bf16x4*)tp;
                }
#pragma unroll
                for (int dt = 0; dt < 4; dt++) {
                    const bf16x4 vf = *(const bf16x4*)&Vsh[dt * 16 + l16][hf * 64 + kvt * 16 + quad * 4];
#pragma unroll
                    for (int mf = 0; mf < 2; mf++)
                        o[mf][dt] = __builtin_amdgcn_mfma_f32_16x16x16bf16_1k(vf, pk[mf], o[mf][dt], 0, 0, 0);
                }
            }
        }
    }

    // ---- epilogue: reduce l across quads, normalize, store O^T ----
#pragma unroll
    for (int mf = 0; mf < 2; mf++) {
        float lt = l_part[mf];
        lt += __shfl_xor(lt, 16, 64);
        lt += __shfl_xor(lt, 32, 64);
        const float inv = 1.f / lt;
        bf16* obase = attn + (long)(b * 2048 + q0 + mf * 16 + l16) * 1024 + h * 64;
#pragma unroll
        for (int dt = 0; dt < 4; dt++) {
            bf16 t4[4];
#pragma unroll
            for (int r = 0; r < 4; r++) t4[r] = __float2bfloat16(o[mf][dt][r] * inv);
            *(uint2*)(obase + dt * 16 + quad * 4) = *(uint2*)t4;
        }
    }
}

// ---------------- launch ----------------
extern "C" void kernel_launch(void* const* d_in, const int* in_sizes, int n_in,
                              void* d_out, int out_size, void* d_ws, size_t ws_size,
                              hipStream_t stream) {
    const float* x  = (const float*)d_in[0];
    const float* wq = (const float*)d_in[1];
    const float* wk = (const float*)d_in[2];
    const float* wv = (const float*)d_in[3];
    const float* wo = (const float*)d_in[4];
    float* out = (float*)d_out;

    char* ws = (char*)d_ws;
    bf16* xb     = (bf16*)(ws);                       // 8192*1024
    bf16* wqkvT  = (bf16*)(ws + 16777216);            // 1536*1024
    bf16* woT    = (bf16*)(ws + 19922944);            // 1024*1024
    bf16* qkv    = (bf16*)(ws + 22020096);            // 8192*1536
    bf16* vt     = (bf16*)(ws + 47185920);            // 4*4*64*2048
    bf16* attn   = (bf16*)(ws + 51380224);            // 8192*1024

    cast_f32_bf16<<<8192, 256, 0, stream>>>(x, xb, 2097152);

    transpose_cast<<<dim3(32, 32), 256, 0, stream>>>(wq, 1024, 1024, wqkvT);
    transpose_cast<<<dim3(8, 32),  256, 0, stream>>>(wk, 1024, 256,  wqkvT + 1024 * 1024);
    transpose_cast<<<dim3(8, 32),  256, 0, stream>>>(wv, 1024, 256,  wqkvT + 1280 * 1024);
    transpose_cast<<<dim3(32, 32), 256, 0, stream>>>(wo, 1024, 1024, woT);

    gemm_bt<true><<<dim3(64, 12), 256, 0, stream>>>(xb, wqkvT, qkv, 8192, 1536, 1024);

    transpose_v<<<dim3(32, 4, 4), 256, 0, stream>>>(qkv, vt);

    attn_kernel<<<dim3(16, 16, 4), 256, 0, stream>>>(qkv, vt, attn);

    gemm_bt<false><<<dim3(64, 8), 256, 0, stream>>>(attn, woT, out, 8192, 1024, 1024);
}